// Round 20
// baseline (103.499 us; speedup 1.0000x reference)
//
#include <hip/hip_runtime.h>
#include <hip/hip_fp16.h>

#define NPAIRS 524288
#define NATOMS 16384
#define TBINS  1024
#define TROWS  1025           // rows 0..1024; row 1024 (d=5) is exactly 0 (fc=0)
#define CAP    80             // max stored neighbors per atom
#define CUTOFF_F 5.0f

// mega grid partition
#define NTBL     65                        // table blocks per layer (16 entries each)
#define MB_G0    256                       // gemm0 blocks
#define MB_TAB   (MB_G0 + 3 * NTBL)        // 256 + 195 = 451
#define MB_WC    (MB_TAB + 72)             // weight convert -> 523
#define MB_TOTAL (MB_WC + 2048)            // pairs -> 2571

typedef _Float16 f16;
typedef f16 f16x4 __attribute__((ext_vector_type(4)));
typedef f16 f16x8 __attribute__((ext_vector_type(8)));
typedef float f32x4 __attribute__((ext_vector_type(4)));

__device__ __forceinline__ float sspf(float v) {
  float a = fabsf(v);
  return fmaxf(v, 0.0f) + log1pf(expf(-a)) - 0.69314718055994531f;
}

// full-K fp16 tile [rows][128], XOR-swizzled, row stride 256 B
__device__ __forceinline__ int swz(int row, int kh) {
  return (row << 8) + ((kh << 1) ^ ((row & 7) << 4));
}
// half-K fp16 W tile [col][64], row stride 128 B (layout of wsw halves)
__device__ __forceinline__ int swzW(int col, int kh) {
  return (col << 7) + ((kh << 1) ^ ((col & 7) << 4));
}
// fetch W fragment (col, k=ss*32+hi*8) directly from global wsw
__device__ __forceinline__ f16x8 ldW(const f16* __restrict__ Wg, int col, int ss, int hi) {
  return *(const f16x8*)((const char*)Wg + (ss >> 1) * 16384 + swzW(col, (ss & 1) * 32 + hi * 8));
}

__device__ __forceinline__ uint4 ldtab(const f16* __restrict__ tabL, int v, int c) {
  return *(const uint4*)(tabL + ((unsigned)(v >> 14) << 7) + (c << 3));
}
__device__ __forceinline__ uint4 ldh(const f16* __restrict__ hin, int v, int c) {
  return *(const uint4*)(hin + ((unsigned)(v & 16383) << 7) + (c << 3));
}
// fp32 accumulate from fp16 operands (v_fma_mix pattern)
__device__ __forceinline__ void dot8(float* acc, uint4 wv, uint4 hv) {
  const __half* wp = (const __half*)&wv;
  const __half* hp = (const __half*)&hv;
  #pragma unroll
  for (int q = 0; q < 8; ++q)
    acc[q] = fmaf(__half2float(wp[q]), __half2float(hp[q]), acc[q]);
}

// ============ zero cursor ============
__global__ __launch_bounds__(256) void zero_kernel(int* __restrict__ p) {
  p[blockIdx.x * 256 + threadIdx.x] = 0;
}

// ============ mega: gemm0 | MFMA table gen | weight convert | pair placement ============
__global__ __launch_bounds__(256) void mega(const int* __restrict__ Z,
                                            const float* __restrict__ emb,
                                            const float* __restrict__ in2f_W,
                                            const float* __restrict__ in2f_b,
                                            const float* __restrict__ fW1,
                                            const float* __restrict__ fb1,
                                            const float* __restrict__ fW2,
                                            const float* __restrict__ fb2,
                                            const float* __restrict__ oW1,
                                            const float* __restrict__ oW2,
                                            const int* __restrict__ idx_i,
                                            const int* __restrict__ idx_j,
                                            const float* __restrict__ R,
                                            f16* __restrict__ table,
                                            f16* __restrict__ wsw,
                                            int* __restrict__ cursor,
                                            int* __restrict__ pjd,
                                            f16* __restrict__ hout) {
  __shared__ char smem[20480];
  int t = threadIdx.x;
  int bid = blockIdx.x;

  if (bid < MB_G0) {
    // ---- gemm0: h0 = fp16(emb[Z] @ W0 + b0), W0 self-converted into LDS ----
    char* Wl = smem;
    size_t rbase = (size_t)bid * 64;
    int w = t >> 6, lane = t & 63;
    int lo = lane & 15, hi = lane >> 4;

    int z = Z[rbase + 16 * w + lo];
    const float* erow = emb + (size_t)z * 128;
    f16x8 fa[4];
    #pragma unroll
    for (int ss = 0; ss < 4; ++ss) {
      float4 a = *(const float4*)(erow + ss * 32 + hi * 8);
      float4 b = *(const float4*)(erow + ss * 32 + hi * 8 + 4);
      f16x8 v = { (f16)a.x, (f16)a.y, (f16)a.z, (f16)a.w,
                  (f16)b.x, (f16)b.y, (f16)b.z, (f16)b.w };
      fa[ss] = v;
    }

    f32x4 acc[8];
    #pragma unroll
    for (int cb = 0; cb < 8; ++cb) acc[cb] = (f32x4){0.0f, 0.0f, 0.0f, 0.0f};

    #pragma unroll
    for (int h = 0; h < 2; ++h) {
      #pragma unroll
      for (int i = 0; i < 4; ++i) {
        int tloc = i * 256 + t;
        int col = tloc & 127, kc = tloc >> 7;
        f16x8 v;
        #pragma unroll
        for (int kk = 0; kk < 8; ++kk)
          v[kk] = (f16)in2f_W[(h * 64 + kc * 8 + kk) * 128 + col];
        *(f16x8*)(Wl + swzW(col, kc * 8)) = v;
      }
      __syncthreads();
      #pragma unroll
      for (int cb = 0; cb < 8; ++cb) {
        int col = cb * 16 + lo;
        #pragma unroll
        for (int sh = 0; sh < 2; ++sh) {
          f16x8 fb = *(f16x8*)(Wl + swzW(col, sh * 32 + hi * 8));
          acc[cb] = __builtin_amdgcn_mfma_f32_16x16x32_f16(fa[h * 2 + sh], fb, acc[cb], 0, 0, 0);
        }
      }
      __syncthreads();
    }

    #pragma unroll
    for (int cb = 0; cb < 8; ++cb) {
      int col = cb * 16 + lo;
      float bc = in2f_b[col];
      #pragma unroll
      for (int j = 0; j < 4; ++j)
        hout[(rbase + 16 * w + hi * 4 + j) * 128 + col] = (f16)(acc[cb][j] + bc);
    }
    return;
  }

  if (bid < MB_TAB) {
    // ---- MFMA table gen: 16 entries/block; hid[16x128]fp16 @ W2 (LDS-staged halves) ----
    char* Al = smem;            // 4 KB: hid tile [16][128] fp16 swz
    char* Wl = smem + 4096;     // 16 KB: half-K W2 fp16 swzW
    int bid2 = bid - MB_G0;
    int l = bid2 / NTBL, rem = bid2 % NTBL;
    int e16 = rem * 16;
    const float* W1 = fW1 + (size_t)l * 20 * 128;
    const float* B1 = fb1 + (size_t)l * 128;
    const float* W2 = fW2 + (size_t)l * 128 * 128;
    const float* B2 = fb2 + (size_t)l * 128;
    const float width = CUTOFF_F / 19.0f;
    const float coeff = -0.5f / (width * width);
    const float dstep = CUTOFF_F / (float)TBINS;

    // phase A: hid = ssp(rbf @ fW1 + b1) -> Al (thread: entry e, 8 cols at q*8)
    {
      int e = t >> 4, q = t & 15;
      float d = (float)(e16 + e) * dstep;
      float rbf[20];
      #pragma unroll
      for (int r = 0; r < 20; ++r) {
        float diff = d - (float)r * width;
        rbf[r] = expf(coeff * diff * diff);
      }
      float4 hA = *(const float4*)&B1[q * 8];
      float4 hB = *(const float4*)&B1[q * 8 + 4];
      #pragma unroll
      for (int r = 0; r < 20; ++r) {
        float4 wa = *(const float4*)&W1[r * 128 + q * 8];
        float4 wb = *(const float4*)&W1[r * 128 + q * 8 + 4];
        hA.x += rbf[r] * wa.x; hA.y += rbf[r] * wa.y;
        hA.z += rbf[r] * wa.z; hA.w += rbf[r] * wa.w;
        hB.x += rbf[r] * wb.x; hB.y += rbf[r] * wb.y;
        hB.z += rbf[r] * wb.z; hB.w += rbf[r] * wb.w;
      }
      f16x8 hv = { (f16)sspf(hA.x), (f16)sspf(hA.y), (f16)sspf(hA.z), (f16)sspf(hA.w),
                   (f16)sspf(hB.x), (f16)sspf(hB.y), (f16)sspf(hB.z), (f16)sspf(hB.w) };
      *(f16x8*)(Al + swz(e, q * 8)) = hv;
    }
    __syncthreads();

    int w = t >> 6, lane = t & 63;
    int lo = lane & 15, hi = lane >> 4;
    f32x4 acc[2];
    acc[0] = (f32x4){0.0f, 0.0f, 0.0f, 0.0f};
    acc[1] = (f32x4){0.0f, 0.0f, 0.0f, 0.0f};

    #pragma unroll
    for (int halfk = 0; halfk < 2; ++halfk) {
      #pragma unroll
      for (int i = 0; i < 4; ++i) {
        int tloc = i * 256 + t;
        int col = tloc & 127, kc = tloc >> 7;
        f16x8 v;
        #pragma unroll
        for (int kk = 0; kk < 8; ++kk)
          v[kk] = (f16)W2[(halfk * 64 + kc * 8 + kk) * 128 + col];
        *(f16x8*)(Wl + swzW(col, kc * 8)) = v;
      }
      __syncthreads();
      #pragma unroll
      for (int cb = 0; cb < 2; ++cb) {
        int col = (w * 2 + cb) * 16 + lo;
        #pragma unroll
        for (int sh = 0; sh < 2; ++sh) {
          int ss = halfk * 2 + sh;
          f16x8 fa = *(f16x8*)(Al + swz(lo, ss * 32 + hi * 8));
          f16x8 fb = *(f16x8*)(Wl + swzW(col, sh * 32 + hi * 8));
          acc[cb] = __builtin_amdgcn_mfma_f32_16x16x32_f16(fa, fb, acc[cb], 0, 0, 0);
        }
      }
      __syncthreads();
    }

    #pragma unroll
    for (int cb = 0; cb < 2; ++cb) {
      int col = (w * 2 + cb) * 16 + lo;
      float bc = B2[col];
      #pragma unroll
      for (int j = 0; j < 4; ++j) {
        int ti = e16 + hi * 4 + j;
        if (ti < TROWS) {
          float d = (float)ti * dstep;
          float fc = (d < CUTOFF_F) ? 0.5f * (cosf(d * 0.62831853071795865f) + 1.0f) : 0.0f;
          ((f16*)table)[((size_t)l * TROWS + ti) * 128 + col] = (f16)((acc[cb][j] + bc) * fc);
        }
      }
    }
    return;
  }

  if (bid < MB_WC) {
    // ---- weight convert: 9 matrices -> wsw fp16 [col][k] in two swzW halves ----
    int bid2 = bid - MB_TAB;
    int mm = bid2 >> 3;
    int tloc = (bid2 & 7) * 256 + t;
    int col = tloc & 127, k0 = (tloc >> 7) << 3;
    const float* src = mm < 3 ? in2f_W + (size_t)mm * 16384
                     : mm < 6 ? oW1 + (size_t)(mm - 3) * 16384
                              : oW2 + (size_t)(mm - 6) * 16384;
    f16x8 v;
    #pragma unroll
    for (int kk = 0; kk < 8; ++kk) v[kk] = (f16)src[(k0 + kk) * 128 + col];
    *(f16x8*)((char*)wsw + (size_t)mm * 32768 + (k0 >> 6) * 16384 + swzW(col, k0 & 63)) = v;
    return;
  }

  // ---- pair placement: store packed (j | bin<<14) ----
  {
    int p = (bid - MB_WC) * 256 + t;
    int i = idx_i[p], j = idx_j[p];
    float dx = R[(size_t)i*3+0] - R[(size_t)j*3+0];
    float dy = R[(size_t)i*3+1] - R[(size_t)j*3+1];
    float dz = R[(size_t)i*3+2] - R[(size_t)j*3+2];
    float d = sqrtf(dx*dx + dy*dy + dz*dz);
    if (d < CUTOFF_F) {
      int bin = __float2int_rn(d * ((float)TBINS / CUTOFF_F));
      int slot = atomicAdd(&cursor[i], 1);
      if (slot < CAP) pjd[i * CAP + slot] = j | (bin << 14);
    }
  }
}

// ============ aggfuse: 16 atoms/block, 1024 thr (wave = 1 atom), 8 KB LDS ============
template <int FIRST, int HAS_NEXT>
__global__ __launch_bounds__(1024, 8) void aggfuse(const int* __restrict__ pjd,
                                                   const int* __restrict__ cnt,
                                                   const f16* __restrict__ hin,
                                                   const f16* __restrict__ tabL,
                                                   const f16* __restrict__ W1g,
                                                   const float* __restrict__ ob1,
                                                   const f16* __restrict__ W2g,
                                                   const float* __restrict__ ob2,
                                                   const int* __restrict__ Z,
                                                   const float* __restrict__ emb,
                                                   float* __restrict__ x,
                                                   const f16* __restrict__ Wng,
                                                   const float* __restrict__ bn,
                                                   f16* __restrict__ hout) {
  __shared__ char smem[8192];
  char* AlT = smem;            // 4 KB: 16-row fp16 A-tile
  char* Tl  = smem + 4096;     // 4 KB: hidden tile
  int tid = threadIdx.x;
  int wv = tid >> 6, lane = tid & 63;
  int g = lane >> 4, c = lane & 15;   // slot 0..3, col group
  int rbase = blockIdx.x * 16;
  const int S = (TBINS << 14);   // sentinel -> zero table row, h[0]

  // ---- agg phase: wave = 1 atom; 4 slots x 2 chains = 8 pairs/iter; m = ceil(n/8) ----
  {
    int a = rbase + wv;
    const int* pp = pjd + a * CAP;
    int n = min(cnt[a], CAP);
    int nh = g * 2;                    // chain base for this slot
    int m = (n + 7) >> 3;              // same for all 64 lanes — no shuffle needed

    float acc[8];
    #pragma unroll
    for (int q = 0; q < 8; ++q) acc[q] = 0.0f;

    int vA  = (nh      < n) ? pp[nh]      : S;
    int vB  = (nh + 1  < n) ? pp[nh + 1]  : S;
    int vA1 = (nh + 8  < n) ? pp[nh + 8]  : S;
    int vB1 = (nh + 9  < n) ? pp[nh + 9]  : S;
    uint4 wA = ldtab(tabL, vA, c), hA = ldh(hin, vA, c);
    uint4 wB = ldtab(tabL, vB, c), hB = ldh(hin, vB, c);

    for (int it = 0; it < m; ++it) {
      int k2 = 8 * (it + 2) + nh;
      int vA2 = (k2 < n)     ? pp[k2]     : S;
      int vB2 = (k2 + 1 < n) ? pp[k2 + 1] : S;
      uint4 wAn = ldtab(tabL, vA1, c), hAn = ldh(hin, vA1, c);
      uint4 wBn = ldtab(tabL, vB1, c), hBn = ldh(hin, vB1, c);
      dot8(acc, wA, hA);
      dot8(acc, wB, hB);
      wA = wAn; hA = hAn; wB = wBn; hB = hBn;
      vA1 = vA2; vB1 = vB2;
    }

    // sum the 4 slots
    #pragma unroll
    for (int q = 0; q < 8; ++q) {
      acc[q] += __shfl_xor(acc[q], 16, 64);
      acc[q] += __shfl_xor(acc[q], 32, 64);
    }

    if (g == 0) {
      f16x8 pk;
      #pragma unroll
      for (int q = 0; q < 8; ++q) pk[q] = (f16)acc[q];
      *(f16x8*)(AlT + swz(wv, c * 8)) = pk;
    }
  }
  __syncthreads();

  // ---- fuse phase: waves 0-7 compute (wave wv owns cols wv*16..wv*16+15, rows 0..15) ----
  int lo = c, hi = g;
  int col = wv * 16 + lo;
  bool act = (wv < 8);

  float res[4];
  if (act) {
    if (FIRST) {
      #pragma unroll
      for (int j = 0; j < 4; ++j) {
        int z = Z[rbase + hi * 4 + j];
        res[j] = emb[(size_t)z * 128 + col];
      }
    } else {
      #pragma unroll
      for (int j = 0; j < 4; ++j)
        res[j] = x[(size_t)(rbase + hi * 4 + j) * 128 + col];
    }

    // gemm1: Tl = ssp(AlT @ oW1 + b1)
    f32x4 acc = {0.0f, 0.0f, 0.0f, 0.0f};
    #pragma unroll
    for (int ss = 0; ss < 4; ++ss) {
      f16x8 fa = *(f16x8*)(AlT + swz(lo, ss * 32 + hi * 8));
      acc = __builtin_amdgcn_mfma_f32_16x16x32_f16(fa, ldW(W1g, col, ss, hi), acc, 0, 0, 0);
    }
    float bc = ob1[col];
    #pragma unroll
    for (int j = 0; j < 4; ++j)
      *(f16*)(Tl + swz(hi * 4 + j, col)) = (f16)sspf(acc[j] + bc);
  }
  __syncthreads();

  // gemm2: x_new = res + Tl @ oW2 + b2 -> x (global) and AlT (next A)
  if (act) {
    f32x4 acc = {0.0f, 0.0f, 0.0f, 0.0f};
    #pragma unroll
    for (int ss = 0; ss < 4; ++ss) {
      f16x8 fa = *(f16x8*)(Tl + swz(lo, ss * 32 + hi * 8));
      acc = __builtin_amdgcn_mfma_f32_16x16x32_f16(fa, ldW(W2g, col, ss, hi), acc, 0, 0, 0);
    }
    float bc = ob2[col];
    #pragma unroll
    for (int j = 0; j < 4; ++j) {
      int r = hi * 4 + j;
      float xn = res[j] + acc[j] + bc;
      x[(size_t)(rbase + r) * 128 + col] = xn;
      if (HAS_NEXT) *(f16*)(AlT + swz(r, col)) = (f16)xn;
    }
  }

  if (HAS_NEXT) {
    __syncthreads();
    if (act) {
      f32x4 acc = {0.0f, 0.0f, 0.0f, 0.0f};
      #pragma unroll
      for (int ss = 0; ss < 4; ++ss) {
        f16x8 fa = *(f16x8*)(AlT + swz(lo, ss * 32 + hi * 8));
        acc = __builtin_amdgcn_mfma_f32_16x16x32_f16(fa, ldW(Wng, col, ss, hi), acc, 0, 0, 0);
      }
      float bc = bn[col];
      #pragma unroll
      for (int j = 0; j < 4; ++j)
        hout[(size_t)(rbase + hi * 4 + j) * 128 + col] = (f16)(acc[j] + bc);
    }
  }
}

// ============ launcher ============
extern "C" void kernel_launch(void* const* d_in, const int* in_sizes, int n_in,
                              void* d_out, int out_size, void* d_ws, size_t ws_size,
                              hipStream_t stream) {
  const int*   Z      = (const int*)d_in[0];
  const float* R      = (const float*)d_in[1];
  const int*   idx_i  = (const int*)d_in[2];
  const int*   idx_j  = (const int*)d_in[3];
  const float* emb    = (const float*)d_in[4];
  const float* in2f_W = (const float*)d_in[5];
  const float* in2f_b = (const float*)d_in[6];
  const float* fW1    = (const float*)d_in[7];
  const float* fb1    = (const float*)d_in[8];
  const float* fW2    = (const float*)d_in[9];
  const float* fb2    = (const float*)d_in[10];
  const float* oW1    = (const float*)d_in[11];
  const float* ob1    = (const float*)d_in[12];
  const float* oW2    = (const float*)d_in[13];
  const float* ob2    = (const float*)d_in[14];
  float* x = (float*)d_out;

  // Workspace layout (non-overlapping; verified):
  //   cursor 0x000000 + 0x010000              = 0x010000
  //   pjd    0x010000 + 16384*80*4 (0x500000) = 0x510000
  //   table  0x520000 + 3*1025*256 (0x0C0300) = 0x5E0300
  //   h0     0x600000 + 0x400000              = 0xA00000
  //   h1     0xA00000 + 0x400000              = 0xE00000
  //   wsw    0xE00000 + 9*32768   (0x048000)  = 0xE48000
  char* ws = (char*)d_ws;
  int*  cursor = (int*) (ws + 0x000000);
  int*  pjd    = (int*) (ws + 0x010000);
  f16*  table  = (f16*) (ws + 0x520000);
  f16*  h0     = (f16*) (ws + 0x600000);
  f16*  h1     = (f16*) (ws + 0xA00000);
  f16*  wsw    = (f16*) (ws + 0xE00000);

  zero_kernel<<<NATOMS / 256, 256, 0, stream>>>(cursor);
  mega<<<MB_TOTAL, 256, 0, stream>>>(Z, emb, in2f_W, in2f_b, fW1, fb1, fW2, fb2,
                                     oW1, oW2, idx_i, idx_j, R,
                                     table, wsw, cursor, pjd, h0);

  aggfuse<1, 1><<<NATOMS / 16, 1024, 0, stream>>>(pjd, cursor, h0, table + 0 * (size_t)TROWS * 128,
                                                  wsw + 3 * 16384, ob1,
                                                  wsw + 6 * 16384, ob2,
                                                  Z, emb, x,
                                                  wsw + 1 * 16384, in2f_b + 128, h1);
  aggfuse<0, 1><<<NATOMS / 16, 1024, 0, stream>>>(pjd, cursor, h1, table + 1 * (size_t)TROWS * 128,
                                                  wsw + 4 * 16384, ob1 + 128,
                                                  wsw + 7 * 16384, ob2 + 128,
                                                  Z, emb, x,
                                                  wsw + 2 * 16384, in2f_b + 256, h0);
  aggfuse<0, 0><<<NATOMS / 16, 1024, 0, stream>>>(pjd, cursor, h0, table + 2 * (size_t)TROWS * 128,
                                                  wsw + 5 * 16384, ob1 + 256,
                                                  wsw + 8 * 16384, ob2 + 256,
                                                  Z, emb, x, nullptr, nullptr, nullptr);
}

// Round 21
// 101.314 us; speedup vs baseline: 1.0216x; 1.0216x over previous
//
#include <hip/hip_runtime.h>
#include <hip/hip_fp16.h>

#define NPAIRS 524288
#define NATOMS 16384
#define TBINS  1024
#define TROWS  1025           // rows 0..1024; row 1024 (d=5) is exactly 0 (fc=0)
#define CAP    80             // max stored neighbors per atom
#define CUTOFF_F 5.0f

// mega grid partition
#define NTBL     65                        // table blocks per layer (16 entries each)
#define MB_G0    256                       // gemm0 blocks
#define MB_TAB   (MB_G0 + 3 * NTBL)        // 256 + 195 = 451
#define MB_WC    (MB_TAB + 72)             // weight convert -> 523
#define MB_TOTAL (MB_WC + 2048)            // pairs -> 2571

typedef _Float16 f16;
typedef f16 f16x4 __attribute__((ext_vector_type(4)));
typedef f16 f16x8 __attribute__((ext_vector_type(8)));
typedef float f32x4 __attribute__((ext_vector_type(4)));

__device__ __forceinline__ float sspf(float v) {
  float a = fabsf(v);
  return fmaxf(v, 0.0f) + log1pf(expf(-a)) - 0.69314718055994531f;
}

// full-K fp16 tile [rows][128], XOR-swizzled, row stride 256 B
__device__ __forceinline__ int swz(int row, int kh) {
  return (row << 8) + ((kh << 1) ^ ((row & 7) << 4));
}
// half-K fp16 W tile [col][64], row stride 128 B (layout of wsw halves)
__device__ __forceinline__ int swzW(int col, int kh) {
  return (col << 7) + ((kh << 1) ^ ((col & 7) << 4));
}
// fetch W fragment (col, k=ss*32+hi*8) directly from global wsw
__device__ __forceinline__ f16x8 ldW(const f16* __restrict__ Wg, int col, int ss, int hi) {
  return *(const f16x8*)((const char*)Wg + (ss >> 1) * 16384 + swzW(col, (ss & 1) * 32 + hi * 8));
}

__device__ __forceinline__ uint4 ldtab(const f16* __restrict__ tabL, int v, int c) {
  return *(const uint4*)(tabL + ((unsigned)(v >> 14) << 7) + (c << 3));
}
__device__ __forceinline__ uint4 ldh(const f16* __restrict__ hin, int v, int c) {
  return *(const uint4*)(hin + ((unsigned)(v & 16383) << 7) + (c << 3));
}
// fp32 accumulate from fp16 operands (v_fma_mix pattern)
__device__ __forceinline__ void dot8(float* acc, uint4 wv, uint4 hv) {
  const __half* wp = (const __half*)&wv;
  const __half* hp = (const __half*)&hv;
  #pragma unroll
  for (int q = 0; q < 8; ++q)
    acc[q] = fmaf(__half2float(wp[q]), __half2float(hp[q]), acc[q]);
}

// ============ zero cursor ============
__global__ __launch_bounds__(256) void zero_kernel(int* __restrict__ p) {
  p[blockIdx.x * 256 + threadIdx.x] = 0;
}

// ============ mega: gemm0 | MFMA table gen | weight convert | pair placement ============
__global__ __launch_bounds__(256) void mega(const int* __restrict__ Z,
                                            const float* __restrict__ emb,
                                            const float* __restrict__ in2f_W,
                                            const float* __restrict__ in2f_b,
                                            const float* __restrict__ fW1,
                                            const float* __restrict__ fb1,
                                            const float* __restrict__ fW2,
                                            const float* __restrict__ fb2,
                                            const float* __restrict__ oW1,
                                            const float* __restrict__ oW2,
                                            const int* __restrict__ idx_i,
                                            const int* __restrict__ idx_j,
                                            const float* __restrict__ R,
                                            f16* __restrict__ table,
                                            f16* __restrict__ wsw,
                                            int* __restrict__ cursor,
                                            int* __restrict__ pjd,
                                            f16* __restrict__ hout) {
  __shared__ char smem[20480];
  int t = threadIdx.x;
  int bid = blockIdx.x;

  if (bid < MB_G0) {
    // ---- gemm0: h0 = fp16(emb[Z] @ W0 + b0), W0 self-converted into LDS ----
    char* Wl = smem;
    size_t rbase = (size_t)bid * 64;
    int w = t >> 6, lane = t & 63;
    int lo = lane & 15, hi = lane >> 4;

    int z = Z[rbase + 16 * w + lo];
    const float* erow = emb + (size_t)z * 128;
    f16x8 fa[4];
    #pragma unroll
    for (int ss = 0; ss < 4; ++ss) {
      float4 a = *(const float4*)(erow + ss * 32 + hi * 8);
      float4 b = *(const float4*)(erow + ss * 32 + hi * 8 + 4);
      f16x8 v = { (f16)a.x, (f16)a.y, (f16)a.z, (f16)a.w,
                  (f16)b.x, (f16)b.y, (f16)b.z, (f16)b.w };
      fa[ss] = v;
    }

    f32x4 acc[8];
    #pragma unroll
    for (int cb = 0; cb < 8; ++cb) acc[cb] = (f32x4){0.0f, 0.0f, 0.0f, 0.0f};

    #pragma unroll
    for (int h = 0; h < 2; ++h) {
      #pragma unroll
      for (int i = 0; i < 4; ++i) {
        int tloc = i * 256 + t;
        int col = tloc & 127, kc = tloc >> 7;
        f16x8 v;
        #pragma unroll
        for (int kk = 0; kk < 8; ++kk)
          v[kk] = (f16)in2f_W[(h * 64 + kc * 8 + kk) * 128 + col];
        *(f16x8*)(Wl + swzW(col, kc * 8)) = v;
      }
      __syncthreads();
      #pragma unroll
      for (int cb = 0; cb < 8; ++cb) {
        int col = cb * 16 + lo;
        #pragma unroll
        for (int sh = 0; sh < 2; ++sh) {
          f16x8 fb = *(f16x8*)(Wl + swzW(col, sh * 32 + hi * 8));
          acc[cb] = __builtin_amdgcn_mfma_f32_16x16x32_f16(fa[h * 2 + sh], fb, acc[cb], 0, 0, 0);
        }
      }
      __syncthreads();
    }

    #pragma unroll
    for (int cb = 0; cb < 8; ++cb) {
      int col = cb * 16 + lo;
      float bc = in2f_b[col];
      #pragma unroll
      for (int j = 0; j < 4; ++j)
        hout[(rbase + 16 * w + hi * 4 + j) * 128 + col] = (f16)(acc[cb][j] + bc);
    }
    return;
  }

  if (bid < MB_TAB) {
    // ---- MFMA table gen: 16 entries/block; hid[16x128]fp16 @ W2 (LDS-staged halves) ----
    char* Al = smem;            // 4 KB: hid tile [16][128] fp16 swz
    char* Wl = smem + 4096;     // 16 KB: half-K W2 fp16 swzW
    int bid2 = bid - MB_G0;
    int l = bid2 / NTBL, rem = bid2 % NTBL;
    int e16 = rem * 16;
    const float* W1 = fW1 + (size_t)l * 20 * 128;
    const float* B1 = fb1 + (size_t)l * 128;
    const float* W2 = fW2 + (size_t)l * 128 * 128;
    const float* B2 = fb2 + (size_t)l * 128;
    const float width = CUTOFF_F / 19.0f;
    const float coeff = -0.5f / (width * width);
    const float dstep = CUTOFF_F / (float)TBINS;

    // phase A: hid = ssp(rbf @ fW1 + b1) -> Al (thread: entry e, 8 cols at q*8)
    {
      int e = t >> 4, q = t & 15;
      float d = (float)(e16 + e) * dstep;
      float rbf[20];
      #pragma unroll
      for (int r = 0; r < 20; ++r) {
        float diff = d - (float)r * width;
        rbf[r] = expf(coeff * diff * diff);
      }
      float4 hA = *(const float4*)&B1[q * 8];
      float4 hB = *(const float4*)&B1[q * 8 + 4];
      #pragma unroll
      for (int r = 0; r < 20; ++r) {
        float4 wa = *(const float4*)&W1[r * 128 + q * 8];
        float4 wb = *(const float4*)&W1[r * 128 + q * 8 + 4];
        hA.x += rbf[r] * wa.x; hA.y += rbf[r] * wa.y;
        hA.z += rbf[r] * wa.z; hA.w += rbf[r] * wa.w;
        hB.x += rbf[r] * wb.x; hB.y += rbf[r] * wb.y;
        hB.z += rbf[r] * wb.z; hB.w += rbf[r] * wb.w;
      }
      f16x8 hv = { (f16)sspf(hA.x), (f16)sspf(hA.y), (f16)sspf(hA.z), (f16)sspf(hA.w),
                   (f16)sspf(hB.x), (f16)sspf(hB.y), (f16)sspf(hB.z), (f16)sspf(hB.w) };
      *(f16x8*)(Al + swz(e, q * 8)) = hv;
    }
    __syncthreads();

    int w = t >> 6, lane = t & 63;
    int lo = lane & 15, hi = lane >> 4;
    f32x4 acc[2];
    acc[0] = (f32x4){0.0f, 0.0f, 0.0f, 0.0f};
    acc[1] = (f32x4){0.0f, 0.0f, 0.0f, 0.0f};

    #pragma unroll
    for (int halfk = 0; halfk < 2; ++halfk) {
      #pragma unroll
      for (int i = 0; i < 4; ++i) {
        int tloc = i * 256 + t;
        int col = tloc & 127, kc = tloc >> 7;
        f16x8 v;
        #pragma unroll
        for (int kk = 0; kk < 8; ++kk)
          v[kk] = (f16)W2[(halfk * 64 + kc * 8 + kk) * 128 + col];
        *(f16x8*)(Wl + swzW(col, kc * 8)) = v;
      }
      __syncthreads();
      #pragma unroll
      for (int cb = 0; cb < 2; ++cb) {
        int col = (w * 2 + cb) * 16 + lo;
        #pragma unroll
        for (int sh = 0; sh < 2; ++sh) {
          int ss = halfk * 2 + sh;
          f16x8 fa = *(f16x8*)(Al + swz(lo, ss * 32 + hi * 8));
          f16x8 fb = *(f16x8*)(Wl + swzW(col, sh * 32 + hi * 8));
          acc[cb] = __builtin_amdgcn_mfma_f32_16x16x32_f16(fa, fb, acc[cb], 0, 0, 0);
        }
      }
      __syncthreads();
    }

    #pragma unroll
    for (int cb = 0; cb < 2; ++cb) {
      int col = (w * 2 + cb) * 16 + lo;
      float bc = B2[col];
      #pragma unroll
      for (int j = 0; j < 4; ++j) {
        int ti = e16 + hi * 4 + j;
        if (ti < TROWS) {
          float d = (float)ti * dstep;
          float fc = (d < CUTOFF_F) ? 0.5f * (cosf(d * 0.62831853071795865f) + 1.0f) : 0.0f;
          ((f16*)table)[((size_t)l * TROWS + ti) * 128 + col] = (f16)((acc[cb][j] + bc) * fc);
        }
      }
    }
    return;
  }

  if (bid < MB_WC) {
    // ---- weight convert: 9 matrices -> wsw fp16 [col][k] in two swzW halves ----
    int bid2 = bid - MB_TAB;
    int mm = bid2 >> 3;
    int tloc = (bid2 & 7) * 256 + t;
    int col = tloc & 127, k0 = (tloc >> 7) << 3;
    const float* src = mm < 3 ? in2f_W + (size_t)mm * 16384
                     : mm < 6 ? oW1 + (size_t)(mm - 3) * 16384
                              : oW2 + (size_t)(mm - 6) * 16384;
    f16x8 v;
    #pragma unroll
    for (int kk = 0; kk < 8; ++kk) v[kk] = (f16)src[(k0 + kk) * 128 + col];
    *(f16x8*)((char*)wsw + (size_t)mm * 32768 + (k0 >> 6) * 16384 + swzW(col, k0 & 63)) = v;
    return;
  }

  // ---- pair placement: store packed (j | bin<<14) ----
  {
    int p = (bid - MB_WC) * 256 + t;
    int i = idx_i[p], j = idx_j[p];
    float dx = R[(size_t)i*3+0] - R[(size_t)j*3+0];
    float dy = R[(size_t)i*3+1] - R[(size_t)j*3+1];
    float dz = R[(size_t)i*3+2] - R[(size_t)j*3+2];
    float d = sqrtf(dx*dx + dy*dy + dz*dz);
    if (d < CUTOFF_F) {
      int bin = __float2int_rn(d * ((float)TBINS / CUTOFF_F));
      int slot = atomicAdd(&cursor[i], 1);
      if (slot < CAP) pjd[i * CAP + slot] = j | (bin << 14);
    }
  }
}

// ============ aggfuse: 16 atoms/block, 512 thr, 8 KB LDS, W from L2 (round-19 winner) ============
template <int FIRST, int HAS_NEXT>
__global__ __launch_bounds__(512, 8) void aggfuse(const int* __restrict__ pjd,
                                                  const int* __restrict__ cnt,
                                                  const f16* __restrict__ hin,
                                                  const f16* __restrict__ tabL,
                                                  const f16* __restrict__ W1g,
                                                  const float* __restrict__ ob1,
                                                  const f16* __restrict__ W2g,
                                                  const float* __restrict__ ob2,
                                                  const int* __restrict__ Z,
                                                  const float* __restrict__ emb,
                                                  float* __restrict__ x,
                                                  const f16* __restrict__ Wng,
                                                  const float* __restrict__ bn,
                                                  f16* __restrict__ hout) {
  __shared__ char smem[8192];
  char* AlT = smem;            // 4 KB: 16-row fp16 A-tile
  char* Tl  = smem + 4096;     // 4 KB: hidden tile
  int tid = threadIdx.x;
  int wv = tid >> 6, lane = tid & 63;
  int s = lane >> 4, c = lane & 15;
  int rbase = blockIdx.x * 16;
  const int S = (TBINS << 14);   // sentinel -> zero table row, h[0]

  // ---- agg phase: wave = 2 atoms x 2 half-slots, fp32 accumulate ----
  {
    int a = rbase + wv * 2 + (s & 1);
    int half = s >> 1;
    const int* pp = pjd + a * CAP;
    int n = min(cnt[a], CAP);
    int nh = half * 2;

    int m = (n + 3) >> 2;
    m = max(m, __shfl_xor(m, 16, 64));
    m = max(m, __shfl_xor(m, 32, 64));

    float acc[8];
    #pragma unroll
    for (int q = 0; q < 8; ++q) acc[q] = 0.0f;

    int vA  = (nh     < n) ? pp[nh]     : S;
    int vB  = (nh + 1 < n) ? pp[nh + 1] : S;
    int vA1 = (nh + 4 < n) ? pp[nh + 4] : S;
    int vB1 = (nh + 5 < n) ? pp[nh + 5] : S;
    uint4 wA = ldtab(tabL, vA, c), hA = ldh(hin, vA, c);
    uint4 wB = ldtab(tabL, vB, c), hB = ldh(hin, vB, c);

    for (int it = 0; it < m; ++it) {
      int k2 = 4 * (it + 2) + nh;
      int vA2 = (k2 < n)     ? pp[k2]     : S;
      int vB2 = (k2 + 1 < n) ? pp[k2 + 1] : S;
      uint4 wAn = ldtab(tabL, vA1, c), hAn = ldh(hin, vA1, c);
      uint4 wBn = ldtab(tabL, vB1, c), hBn = ldh(hin, vB1, c);
      dot8(acc, wA, hA);
      dot8(acc, wB, hB);
      wA = wAn; hA = hAn; wB = wBn; hB = hBn;
      vA1 = vA2; vB1 = vB2;
    }

    #pragma unroll
    for (int q = 0; q < 8; ++q) acc[q] += __shfl_xor(acc[q], 32, 64);

    if (s < 2) {
      int row = wv * 2 + s;
      f16x8 pk;
      #pragma unroll
      for (int q = 0; q < 8; ++q) pk[q] = (f16)acc[q];
      *(f16x8*)(AlT + swz(row, c * 8)) = pk;
    }
  }
  __syncthreads();

  // ---- fuse phase: 8 waves, wave wv owns cols wv*16..wv*16+15, rows 0..15 ----
  int lo = c, hi = s;
  int col = wv * 16 + lo;

  // residual prefetch (hidden under gemm1)
  float res[4];
  if (FIRST) {
    #pragma unroll
    for (int j = 0; j < 4; ++j) {
      int z = Z[rbase + hi * 4 + j];
      res[j] = emb[(size_t)z * 128 + col];
    }
  } else {
    #pragma unroll
    for (int j = 0; j < 4; ++j)
      res[j] = x[(size_t)(rbase + hi * 4 + j) * 128 + col];
  }

  // gemm1: Tl = ssp(AlT @ oW1 + b1)
  {
    f32x4 acc = {0.0f, 0.0f, 0.0f, 0.0f};
    #pragma unroll
    for (int ss = 0; ss < 4; ++ss) {
      f16x8 fa = *(f16x8*)(AlT + swz(lo, ss * 32 + hi * 8));
      acc = __builtin_amdgcn_mfma_f32_16x16x32_f16(fa, ldW(W1g, col, ss, hi), acc, 0, 0, 0);
    }
    float bc = ob1[col];
    #pragma unroll
    for (int j = 0; j < 4; ++j)
      *(f16*)(Tl + swz(hi * 4 + j, col)) = (f16)sspf(acc[j] + bc);
  }
  __syncthreads();

  // gemm2: x_new = res + Tl @ oW2 + b2 -> x (global) and AlT (next A)
  {
    f32x4 acc = {0.0f, 0.0f, 0.0f, 0.0f};
    #pragma unroll
    for (int ss = 0; ss < 4; ++ss) {
      f16x8 fa = *(f16x8*)(Tl + swz(lo, ss * 32 + hi * 8));
      acc = __builtin_amdgcn_mfma_f32_16x16x32_f16(fa, ldW(W2g, col, ss, hi), acc, 0, 0, 0);
    }
    float bc = ob2[col];
    #pragma unroll
    for (int j = 0; j < 4; ++j) {
      int r = hi * 4 + j;
      float xn = res[j] + acc[j] + bc;
      x[(size_t)(rbase + r) * 128 + col] = xn;
      if (HAS_NEXT) *(f16*)(AlT + swz(r, col)) = (f16)xn;
    }
  }

  if (HAS_NEXT) {
    __syncthreads();
    f32x4 acc = {0.0f, 0.0f, 0.0f, 0.0f};
    #pragma unroll
    for (int ss = 0; ss < 4; ++ss) {
      f16x8 fa = *(f16x8*)(AlT + swz(lo, ss * 32 + hi * 8));
      acc = __builtin_amdgcn_mfma_f32_16x16x32_f16(fa, ldW(Wng, col, ss, hi), acc, 0, 0, 0);
    }
    float bc = bn[col];
    #pragma unroll
    for (int j = 0; j < 4; ++j)
      hout[(size_t)(rbase + hi * 4 + j) * 128 + col] = (f16)(acc[j] + bc);
  }
}

// ============ launcher ============
extern "C" void kernel_launch(void* const* d_in, const int* in_sizes, int n_in,
                              void* d_out, int out_size, void* d_ws, size_t ws_size,
                              hipStream_t stream) {
  const int*   Z      = (const int*)d_in[0];
  const float* R      = (const float*)d_in[1];
  const int*   idx_i  = (const int*)d_in[2];
  const int*   idx_j  = (const int*)d_in[3];
  const float* emb    = (const float*)d_in[4];
  const float* in2f_W = (const float*)d_in[5];
  const float* in2f_b = (const float*)d_in[6];
  const float* fW1    = (const float*)d_in[7];
  const float* fb1    = (const float*)d_in[8];
  const float* fW2    = (const float*)d_in[9];
  const float* fb2    = (const float*)d_in[10];
  const float* oW1    = (const float*)d_in[11];
  const float* ob1    = (const float*)d_in[12];
  const float* oW2    = (const float*)d_in[13];
  const float* ob2    = (const float*)d_in[14];
  float* x = (float*)d_out;

  // Workspace layout (non-overlapping; verified):
  //   cursor 0x000000 + 0x010000              = 0x010000
  //   pjd    0x010000 + 16384*80*4 (0x500000) = 0x510000
  //   table  0x520000 + 3*1025*256 (0x0C0300) = 0x5E0300
  //   h0     0x600000 + 0x400000              = 0xA00000
  //   h1     0xA00000 + 0x400000              = 0xE00000
  //   wsw    0xE00000 + 9*32768   (0x048000)  = 0xE48000
  char* ws = (char*)d_ws;
  int*  cursor = (int*) (ws + 0x000000);
  int*  pjd    = (int*) (ws + 0x010000);
  f16*  table  = (f16*) (ws + 0x520000);
  f16*  h0     = (f16*) (ws + 0x600000);
  f16*  h1     = (f16*) (ws + 0xA00000);
  f16*  wsw    = (f16*) (ws + 0xE00000);

  zero_kernel<<<NATOMS / 256, 256, 0, stream>>>(cursor);
  mega<<<MB_TOTAL, 256, 0, stream>>>(Z, emb, in2f_W, in2f_b, fW1, fb1, fW2, fb2,
                                     oW1, oW2, idx_i, idx_j, R,
                                     table, wsw, cursor, pjd, h0);

  aggfuse<1, 1><<<NATOMS / 16, 512, 0, stream>>>(pjd, cursor, h0, table + 0 * (size_t)TROWS * 128,
                                                 wsw + 3 * 16384, ob1,
                                                 wsw + 6 * 16384, ob2,
                                                 Z, emb, x,
                                                 wsw + 1 * 16384, in2f_b + 128, h1);
  aggfuse<0, 1><<<NATOMS / 16, 512, 0, stream>>>(pjd, cursor, h1, table + 1 * (size_t)TROWS * 128,
                                                 wsw + 4 * 16384, ob1 + 128,
                                                 wsw + 7 * 16384, ob2 + 128,
                                                 Z, emb, x,
                                                 wsw + 2 * 16384, in2f_b + 256, h0);
  aggfuse<0, 0><<<NATOMS / 16, 512, 0, stream>>>(pjd, cursor, h0, table + 2 * (size_t)TROWS * 128,
                                                 wsw + 5 * 16384, ob1 + 256,
                                                 wsw + 8 * 16384, ob2 + 256,
                                                 Z, emb, x, nullptr, nullptr, nullptr);
}